// Round 2
// baseline (572.325 us; speedup 1.0000x reference)
//
#include <hip/hip_runtime.h>

#define NN 50000
#define NE 800000
#define FD 128
#define NG 512
#define NC 10

// ---------------- setup: degree, dis, CSR build ----------------

__global__ __launch_bounds__(256) void zero_kernel(int* __restrict__ p, int n) {
  int i = blockIdx.x * 256 + threadIdx.x;
  if (i < n) p[i] = 0;
}

__global__ __launch_bounds__(256) void count_kernel(const int* __restrict__ ei,
                                                    int* __restrict__ cnt) {
  int e = blockIdx.x * 256 + threadIdx.x;
  if (e >= NE) return;
  atomicAdd(&cnt[ei[NE + e]], 1);
}

__global__ __launch_bounds__(256) void dis_kernel(const int* __restrict__ cnt,
                                                  float* __restrict__ dis) {
  int n = blockIdx.x * 256 + threadIdx.x;
  if (n >= NN) return;
  dis[n] = rsqrtf((float)cnt[n] + 1.0f);
}

// single-block exclusive scan over NN counts -> offs[NN+1], cursor copy
__global__ __launch_bounds__(1024) void scan_kernel(const int* __restrict__ cnt,
                                                    int* __restrict__ offs,
                                                    int* __restrict__ cursor) {
  __shared__ int part[1024];
  int tid = threadIdx.x;
  const int chunk = (NN + 1023) / 1024;  // 49
  int start = tid * chunk;
  int s = 0;
  for (int i = 0; i < chunk; ++i) {
    int idx = start + i;
    if (idx < NN) s += cnt[idx];
  }
  part[tid] = s;
  __syncthreads();
  for (int off = 1; off < 1024; off <<= 1) {
    int v = (tid >= off) ? part[tid - off] : 0;
    __syncthreads();
    part[tid] += v;
    __syncthreads();
  }
  int run = part[tid] - s;  // exclusive prefix
  for (int i = 0; i < chunk; ++i) {
    int idx = start + i;
    if (idx < NN) {
      offs[idx] = run;
      cursor[idx] = run;
      run += cnt[idx];
    }
  }
  if (tid == 1023) offs[NN] = run;  // == NE
}

__global__ __launch_bounds__(256) void fill_kernel(const int* __restrict__ ei,
                                                   const float* __restrict__ dis,
                                                   int* __restrict__ cursor,
                                                   int* __restrict__ ssrc,
                                                   float* __restrict__ scoef) {
  int e = blockIdx.x * 256 + threadIdx.x;
  if (e >= NE) return;
  int s = ei[e];
  int d = ei[NE + e];
  int pos = atomicAdd(&cursor[d], 1);
  ssrc[pos] = s;
  scoef[pos] = dis[s] * dis[d];
}

// ---------------- GEMM: H = act(A) @ W  (A: NN x 128, W: 128 x 128) ----------------

__device__ __forceinline__ void fma4(float4& acc, float s, const float4& w) {
  acc.x += s * w.x; acc.y += s * w.y; acc.z += s * w.z; acc.w += s * w.w;
}

#define SA_LDF4 33  // 132 floats per row (pad 4) -> 2-way bank conflict = free

__global__ __launch_bounds__(256) void gemm_kernel(const float* __restrict__ A,
                                                   const float* __restrict__ W,
                                                   float* __restrict__ H,
                                                   int applyRelu) {
  __shared__ float sA[64 * 132];   // 33.8 KB
  __shared__ float sW[128 * 64];   // 32 KB
  float4* sA4 = reinterpret_cast<float4*>(sA);
  float4* sW4 = reinterpret_cast<float4*>(sW);
  const float4* A4 = reinterpret_cast<const float4*>(A);
  const float4* W4 = reinterpret_cast<const float4*>(W);
  int tid = threadIdx.x;
  int rowBase = blockIdx.x * 64;

  // stage A tile (64 rows x 128), relu fused
  for (int i = tid; i < 64 * 32; i += 256) {
    int r = i >> 5, c4 = i & 31;
    int gr = rowBase + r;
    float4 v = make_float4(0.f, 0.f, 0.f, 0.f);
    if (gr < NN) v = A4[gr * 32 + c4];
    if (applyRelu) {
      v.x = fmaxf(v.x, 0.f); v.y = fmaxf(v.y, 0.f);
      v.z = fmaxf(v.z, 0.f); v.w = fmaxf(v.w, 0.f);
    }
    sA4[r * SA_LDF4 + c4] = v;
  }

  int tc = tid & 15;   // col group (4 cols)
  int tr = tid >> 4;   // row group (4 rows)

  for (int half = 0; half < 2; ++half) {
    __syncthreads();   // sA ready (half 0) / sW consumption done (half 1)
    int cb4 = half * 16;
    for (int i = tid; i < 128 * 16; i += 256) {
      int k = i >> 4, c4 = i & 15;
      sW4[i] = W4[k * 32 + cb4 + c4];
    }
    __syncthreads();

    float4 acc0 = make_float4(0,0,0,0), acc1 = make_float4(0,0,0,0);
    float4 acc2 = make_float4(0,0,0,0), acc3 = make_float4(0,0,0,0);
    #pragma unroll 4
    for (int kq = 0; kq < 32; ++kq) {
      float4 w0 = sW4[(kq * 4 + 0) * 16 + tc];
      float4 w1 = sW4[(kq * 4 + 1) * 16 + tc];
      float4 w2 = sW4[(kq * 4 + 2) * 16 + tc];
      float4 w3 = sW4[(kq * 4 + 3) * 16 + tc];
      float4 a;
      a = sA4[(tr * 4 + 0) * SA_LDF4 + kq];
      fma4(acc0, a.x, w0); fma4(acc0, a.y, w1); fma4(acc0, a.z, w2); fma4(acc0, a.w, w3);
      a = sA4[(tr * 4 + 1) * SA_LDF4 + kq];
      fma4(acc1, a.x, w0); fma4(acc1, a.y, w1); fma4(acc1, a.z, w2); fma4(acc1, a.w, w3);
      a = sA4[(tr * 4 + 2) * SA_LDF4 + kq];
      fma4(acc2, a.x, w0); fma4(acc2, a.y, w1); fma4(acc2, a.z, w2); fma4(acc2, a.w, w3);
      a = sA4[(tr * 4 + 3) * SA_LDF4 + kq];
      fma4(acc3, a.x, w0); fma4(acc3, a.y, w1); fma4(acc3, a.z, w2); fma4(acc3, a.w, w3);
    }
    float4* H4 = reinterpret_cast<float4*>(H);
    int gr = rowBase + tr * 4;
    if (gr + 0 < NN) H4[(gr + 0) * 32 + cb4 + tc] = acc0;
    if (gr + 1 < NN) H4[(gr + 1) * 32 + cb4 + tc] = acc1;
    if (gr + 2 < NN) H4[(gr + 2) * 32 + cb4 + tc] = acc2;
    if (gr + 3 < NN) H4[(gr + 3) * 32 + cb4 + tc] = acc3;
  }
}

// ---------------- aggregation ----------------

// agg[n][c] = b[c] + dis[n]^2 * h[n][c]
__global__ __launch_bounds__(256) void agg_init_kernel(const float* __restrict__ H,
                                                       const float* __restrict__ dis,
                                                       const float* __restrict__ b,
                                                       float* __restrict__ AGG) {
  int idx = blockIdx.x * 256 + threadIdx.x;  // over NN*32 float4 groups
  if (idx >= NN * 32) return;
  int n = idx >> 5, c4 = idx & 31;
  float d = dis[n];
  float d2 = d * d;
  float4 h = reinterpret_cast<const float4*>(H)[idx];
  float4 bb = reinterpret_cast<const float4*>(b)[c4];
  float4 o = make_float4(bb.x + d2 * h.x, bb.y + d2 * h.y,
                         bb.z + d2 * h.z, bb.w + d2 * h.w);
  reinterpret_cast<float4*>(AGG)[idx] = o;
}

// one wave per destination node; CSR edges; no atomics
__global__ __launch_bounds__(256) void agg_edge_kernel(const int* __restrict__ offs,
                                                       const int* __restrict__ ssrc,
                                                       const float* __restrict__ scoef,
                                                       const float* __restrict__ H,
                                                       float* __restrict__ AGG) {
  int node = blockIdx.x * 4 + (threadIdx.x >> 6);
  if (node >= NN) return;
  node = __builtin_amdgcn_readfirstlane(node);  // wave-uniform hint -> scalar loads
  int lane = threadIdx.x & 63;
  int beg = offs[node], end = offs[node + 1];
  const float2* H2 = reinterpret_cast<const float2*>(H);
  float2 acc = make_float2(0.f, 0.f);
  for (int j = beg; j < end; ++j) {
    int s = ssrc[j];
    float cf = scoef[j];
    float2 hv = H2[(size_t)s * 64 + lane];
    acc.x += cf * hv.x;
    acc.y += cf * hv.y;
  }
  float2* AGG2 = reinterpret_cast<float2*>(AGG);
  float2 cur = AGG2[(size_t)node * 64 + lane];
  cur.x += acc.x; cur.y += acc.y;
  AGG2[(size_t)node * 64 + lane] = cur;
}

// ---------------- fused pooling + classifier ----------------
// batch is sorted: binary-search the segment for graph g, mean-pool in
// registers across 4 waves, then 128x10 classifier via shuffle reduce.

__device__ __forceinline__ int lower_bound(const int* __restrict__ b, int n, int key) {
  int lo = 0, hi = n;
  while (lo < hi) {
    int m = (lo + hi) >> 1;
    if (b[m] < key) lo = m + 1; else hi = m;
  }
  return lo;
}

__global__ __launch_bounds__(256) void pool_final_kernel(const float* __restrict__ AGG,
                                                         const int* __restrict__ batch,
                                                         const float* __restrict__ Wl,
                                                         const float* __restrict__ bl,
                                                         float* __restrict__ out) {
  int g = blockIdx.x;
  int tid = threadIdx.x;
  int lane = tid & 63, w = tid >> 6;
  int start = lower_bound(batch, NN, g);
  int end = lower_bound(batch, NN, g + 1);

  const float2* AGG2 = reinterpret_cast<const float2*>(AGG);
  float2 acc = make_float2(0.f, 0.f);
  for (int n = start + w; n < end; n += 4) {
    float2 v = AGG2[(size_t)n * 64 + lane];
    acc.x += v.x; acc.y += v.y;
  }
  __shared__ float red[4][FD];
  red[w][lane * 2 + 0] = acc.x;
  red[w][lane * 2 + 1] = acc.y;
  __syncthreads();
  if (w == 0) {
    float px = red[0][lane * 2] + red[1][lane * 2] + red[2][lane * 2] + red[3][lane * 2];
    float py = red[0][lane * 2 + 1] + red[1][lane * 2 + 1] + red[2][lane * 2 + 1] + red[3][lane * 2 + 1];
    float inv = 1.0f / fmaxf((float)(end - start), 1.0f);
    px *= inv; py *= inv;
    float pc[NC];
    #pragma unroll
    for (int c = 0; c < NC; ++c)
      pc[c] = px * Wl[(2 * lane) * NC + c] + py * Wl[(2 * lane + 1) * NC + c];
    #pragma unroll
    for (int off = 32; off > 0; off >>= 1) {
      #pragma unroll
      for (int c = 0; c < NC; ++c) pc[c] += __shfl_down(pc[c], off, 64);
    }
    if (lane == 0) {
      #pragma unroll
      for (int c = 0; c < NC; ++c) out[g * NC + c] = pc[c] + bl[c];
    }
  }
}

// ---------------- launch ----------------

extern "C" void kernel_launch(void* const* d_in, const int* in_sizes, int n_in,
                              void* d_out, int out_size, void* d_ws, size_t ws_size,
                              hipStream_t stream) {
  const float* x       = (const float*)d_in[0];
  const int* ei        = (const int*)d_in[1];    // int32 on device
  const int* batch     = (const int*)d_in[2];    // int32 on device
  const float* W1 = (const float*)d_in[3];
  const float* b1 = (const float*)d_in[4];
  const float* W2 = (const float*)d_in[5];
  const float* b2 = (const float*)d_in[6];
  const float* W3 = (const float*)d_in[7];
  const float* b3 = (const float*)d_in[8];
  const float* Wl = (const float*)d_in[9];
  const float* bl = (const float*)d_in[10];
  float* out = (float*)d_out;

  char* ws = (char*)d_ws;
  size_t o = 0;
  auto alloc = [&](size_t bytes) {
    void* p = ws + o;
    o += bytes;
    o = (o + 255) & ~(size_t)255;
    return p;
  };
  int*   cnt    = (int*)  alloc((size_t)NN * 4);
  int*   offs   = (int*)  alloc((size_t)(NN + 1) * 4);
  int*   cursor = (int*)  alloc((size_t)NN * 4);
  float* dis    = (float*)alloc((size_t)NN * 4);
  int*   ssrc   = (int*)  alloc((size_t)NE * 4);
  float* scoef  = (float*)alloc((size_t)NE * 4);
  float* h      = (float*)alloc((size_t)NN * FD * 4);
  float* agg    = (float*)alloc((size_t)NN * FD * 4);

  zero_kernel<<<(NN + 255) / 256, 256, 0, stream>>>(cnt, NN);
  count_kernel<<<(NE + 255) / 256, 256, 0, stream>>>(ei, cnt);
  dis_kernel<<<(NN + 255) / 256, 256, 0, stream>>>(cnt, dis);
  scan_kernel<<<1, 1024, 0, stream>>>(cnt, offs, cursor);
  fill_kernel<<<(NE + 255) / 256, 256, 0, stream>>>(ei, dis, cursor, ssrc, scoef);

  int gemmGrid = (NN + 63) / 64;
  int nodeGrid = (NN + 3) / 4;
  int initGrid = (NN * 32) / 256;

  // layer 1
  gemm_kernel<<<gemmGrid, 256, 0, stream>>>(x, W1, h, 0);
  agg_init_kernel<<<initGrid, 256, 0, stream>>>(h, dis, b1, agg);
  agg_edge_kernel<<<nodeGrid, 256, 0, stream>>>(offs, ssrc, scoef, h, agg);
  // layer 2
  gemm_kernel<<<gemmGrid, 256, 0, stream>>>(agg, W2, h, 1);
  agg_init_kernel<<<initGrid, 256, 0, stream>>>(h, dis, b2, agg);
  agg_edge_kernel<<<nodeGrid, 256, 0, stream>>>(offs, ssrc, scoef, h, agg);
  // layer 3
  gemm_kernel<<<gemmGrid, 256, 0, stream>>>(agg, W3, h, 1);
  agg_init_kernel<<<initGrid, 256, 0, stream>>>(h, dis, b3, agg);
  agg_edge_kernel<<<nodeGrid, 256, 0, stream>>>(offs, ssrc, scoef, h, agg);

  pool_final_kernel<<<NG, 256, 0, stream>>>(agg, batch, Wl, bl, out);
}

// Round 3
// 401.359 us; speedup vs baseline: 1.4260x; 1.4260x over previous
//
#include <hip/hip_runtime.h>

#define NN 50000
#define NE 800000
#define FD 128
#define NG 512
#define NC 10

#define SCAN_TILE 1024
#define NBLK ((NN + SCAN_TILE - 1) / SCAN_TILE)  // 49

// ---------------- setup: degree, dis, CSR build ----------------

__global__ __launch_bounds__(256) void zero_kernel(int* __restrict__ p, int n) {
  int i = blockIdx.x * 256 + threadIdx.x;
  if (i < n) p[i] = 0;
}

__global__ __launch_bounds__(256) void count_kernel(const int* __restrict__ ei,
                                                    int* __restrict__ cnt) {
  int e = blockIdx.x * 256 + threadIdx.x;
  if (e >= NE) return;
  atomicAdd(&cnt[ei[NE + e]], 1);
}

__global__ __launch_bounds__(256) void dis_kernel(const int* __restrict__ cnt,
                                                  float* __restrict__ dis) {
  int n = blockIdx.x * 256 + threadIdx.x;
  if (n >= NN) return;
  dis[n] = rsqrtf((float)cnt[n] + 1.0f);
}

// --- 3-phase multi-block exclusive scan over cnt[NN] ---

__global__ __launch_bounds__(256) void scan_sum_kernel(const int* __restrict__ cnt,
                                                       int* __restrict__ bsum) {
  __shared__ int red[256];
  int tid = threadIdx.x;
  int base = blockIdx.x * SCAN_TILE + tid * 4;
  int s = 0;
  #pragma unroll
  for (int i = 0; i < 4; ++i) {
    int idx = base + i;
    if (idx < NN) s += cnt[idx];
  }
  red[tid] = s;
  __syncthreads();
  #pragma unroll
  for (int off = 128; off > 0; off >>= 1) {
    if (tid < off) red[tid] += red[tid + off];
    __syncthreads();
  }
  if (tid == 0) bsum[blockIdx.x] = red[0];
}

__global__ __launch_bounds__(64) void scan_bsum_kernel(const int* __restrict__ bsum,
                                                       int* __restrict__ bpre,
                                                       int* __restrict__ offs) {
  int tid = threadIdx.x;
  int orig = (tid < NBLK) ? bsum[tid] : 0;
  int v = orig;
  #pragma unroll
  for (int off = 1; off < 64; off <<= 1) {
    int u = __shfl_up(v, off, 64);
    if (tid >= off) v += u;
  }
  if (tid < NBLK) bpre[tid] = v - orig;   // exclusive
  if (tid == NBLK - 1) offs[NN] = v;      // total == NE
}

__global__ __launch_bounds__(256) void scan_write_kernel(const int* __restrict__ cnt,
                                                         const int* __restrict__ bpre,
                                                         int* __restrict__ offs,
                                                         int* __restrict__ cursor) {
  __shared__ int lds[256];
  int tid = threadIdx.x;
  int base = blockIdx.x * SCAN_TILE + tid * 4;
  int v0 = 0, v1 = 0, v2 = 0, v3 = 0;
  if (base + 0 < NN) v0 = cnt[base + 0];
  if (base + 1 < NN) v1 = cnt[base + 1];
  if (base + 2 < NN) v2 = cnt[base + 2];
  if (base + 3 < NN) v3 = cnt[base + 3];
  int s = v0 + v1 + v2 + v3;
  lds[tid] = s;
  __syncthreads();
  #pragma unroll
  for (int off = 1; off < 256; off <<= 1) {
    int u = (tid >= off) ? lds[tid - off] : 0;
    __syncthreads();
    lds[tid] += u;
    __syncthreads();
  }
  int run = bpre[blockIdx.x] + lds[tid] - s;  // exclusive prefix
  if (base + 0 < NN) { offs[base + 0] = run; cursor[base + 0] = run; run += v0; }
  if (base + 1 < NN) { offs[base + 1] = run; cursor[base + 1] = run; run += v1; }
  if (base + 2 < NN) { offs[base + 2] = run; cursor[base + 2] = run; run += v2; }
  if (base + 3 < NN) { offs[base + 3] = run; cursor[base + 3] = run; run += v3; }
}

__global__ __launch_bounds__(256) void fill_kernel(const int* __restrict__ ei,
                                                   const float* __restrict__ dis,
                                                   int* __restrict__ cursor,
                                                   int* __restrict__ ssrc,
                                                   float* __restrict__ scoef) {
  int e = blockIdx.x * 256 + threadIdx.x;
  if (e >= NE) return;
  int s = ei[e];
  int d = ei[NE + e];
  int pos = atomicAdd(&cursor[d], 1);
  ssrc[pos] = s;
  scoef[pos] = dis[s] * dis[d];
}

// ---------------- GEMM: H = act(A) @ W  (A: NN x 128, W: 128 x 128) ----------------

__device__ __forceinline__ void fma4(float4& acc, float s, const float4& w) {
  acc.x += s * w.x; acc.y += s * w.y; acc.z += s * w.z; acc.w += s * w.w;
}

#define SA_LDF4 33  // 132 floats per row (pad 4) -> 2-way bank conflict = free

__global__ __launch_bounds__(256) void gemm_kernel(const float* __restrict__ A,
                                                   const float* __restrict__ W,
                                                   float* __restrict__ H,
                                                   int applyRelu) {
  __shared__ float sA[64 * 132];   // 33.8 KB
  __shared__ float sW[128 * 64];   // 32 KB
  float4* sA4 = reinterpret_cast<float4*>(sA);
  float4* sW4 = reinterpret_cast<float4*>(sW);
  const float4* A4 = reinterpret_cast<const float4*>(A);
  const float4* W4 = reinterpret_cast<const float4*>(W);
  int tid = threadIdx.x;
  int rowBase = blockIdx.x * 64;

  for (int i = tid; i < 64 * 32; i += 256) {
    int r = i >> 5, c4 = i & 31;
    int gr = rowBase + r;
    float4 v = make_float4(0.f, 0.f, 0.f, 0.f);
    if (gr < NN) v = A4[gr * 32 + c4];
    if (applyRelu) {
      v.x = fmaxf(v.x, 0.f); v.y = fmaxf(v.y, 0.f);
      v.z = fmaxf(v.z, 0.f); v.w = fmaxf(v.w, 0.f);
    }
    sA4[r * SA_LDF4 + c4] = v;
  }

  int tc = tid & 15;
  int tr = tid >> 4;

  for (int half = 0; half < 2; ++half) {
    __syncthreads();
    int cb4 = half * 16;
    for (int i = tid; i < 128 * 16; i += 256) {
      int k = i >> 4, c4 = i & 15;
      sW4[i] = W4[k * 32 + cb4 + c4];
    }
    __syncthreads();

    float4 acc0 = make_float4(0,0,0,0), acc1 = make_float4(0,0,0,0);
    float4 acc2 = make_float4(0,0,0,0), acc3 = make_float4(0,0,0,0);
    #pragma unroll 4
    for (int kq = 0; kq < 32; ++kq) {
      float4 w0 = sW4[(kq * 4 + 0) * 16 + tc];
      float4 w1 = sW4[(kq * 4 + 1) * 16 + tc];
      float4 w2 = sW4[(kq * 4 + 2) * 16 + tc];
      float4 w3 = sW4[(kq * 4 + 3) * 16 + tc];
      float4 a;
      a = sA4[(tr * 4 + 0) * SA_LDF4 + kq];
      fma4(acc0, a.x, w0); fma4(acc0, a.y, w1); fma4(acc0, a.z, w2); fma4(acc0, a.w, w3);
      a = sA4[(tr * 4 + 1) * SA_LDF4 + kq];
      fma4(acc1, a.x, w0); fma4(acc1, a.y, w1); fma4(acc1, a.z, w2); fma4(acc1, a.w, w3);
      a = sA4[(tr * 4 + 2) * SA_LDF4 + kq];
      fma4(acc2, a.x, w0); fma4(acc2, a.y, w1); fma4(acc2, a.z, w2); fma4(acc2, a.w, w3);
      a = sA4[(tr * 4 + 3) * SA_LDF4 + kq];
      fma4(acc3, a.x, w0); fma4(acc3, a.y, w1); fma4(acc3, a.z, w2); fma4(acc3, a.w, w3);
    }
    float4* H4 = reinterpret_cast<float4*>(H);
    int gr = rowBase + tr * 4;
    if (gr + 0 < NN) H4[(gr + 0) * 32 + cb4 + tc] = acc0;
    if (gr + 1 < NN) H4[(gr + 1) * 32 + cb4 + tc] = acc1;
    if (gr + 2 < NN) H4[(gr + 2) * 32 + cb4 + tc] = acc2;
    if (gr + 3 < NN) H4[(gr + 3) * 32 + cb4 + tc] = acc3;
  }
}

// ---------------- fused aggregation (self-loop + bias + edge gather) ----------------
// AGG[n][c] = b[c] + dis[n]^2 * H[n][c] + sum_{e: dst=n} coef_e * H[src_e][c]

__global__ __launch_bounds__(256) void agg_edge_kernel(const int* __restrict__ offs,
                                                       const int* __restrict__ ssrc,
                                                       const float* __restrict__ scoef,
                                                       const float* __restrict__ H,
                                                       const float* __restrict__ dis,
                                                       const float* __restrict__ b,
                                                       float* __restrict__ AGG) {
  int node = blockIdx.x * 4 + (threadIdx.x >> 6);
  if (node >= NN) return;
  node = __builtin_amdgcn_readfirstlane(node);  // wave-uniform -> scalar loads
  int lane = threadIdx.x & 63;
  int beg = offs[node], end = offs[node + 1];
  const float2* H2 = reinterpret_cast<const float2*>(H);

  float d = dis[node];
  float d2 = d * d;
  float2 bb = reinterpret_cast<const float2*>(b)[lane];
  float2 hn = H2[(size_t)node * 64 + lane];
  float2 acc = make_float2(bb.x + d2 * hn.x, bb.y + d2 * hn.y);
  float2 acc2 = make_float2(0.f, 0.f);

  int j = beg;
  for (; j + 1 < end; j += 2) {
    int s0 = ssrc[j], s1 = ssrc[j + 1];
    float c0 = scoef[j], c1 = scoef[j + 1];
    float2 h0 = H2[(size_t)s0 * 64 + lane];
    float2 h1 = H2[(size_t)s1 * 64 + lane];
    acc.x += c0 * h0.x;  acc.y += c0 * h0.y;
    acc2.x += c1 * h1.x; acc2.y += c1 * h1.y;
  }
  if (j < end) {
    int s0 = ssrc[j];
    float c0 = scoef[j];
    float2 h0 = H2[(size_t)s0 * 64 + lane];
    acc.x += c0 * h0.x; acc.y += c0 * h0.y;
  }
  acc.x += acc2.x; acc.y += acc2.y;
  reinterpret_cast<float2*>(AGG)[(size_t)node * 64 + lane] = acc;
}

// ---------------- fused pooling + classifier ----------------

__device__ __forceinline__ int lower_bound(const int* __restrict__ b, int n, int key) {
  int lo = 0, hi = n;
  while (lo < hi) {
    int m = (lo + hi) >> 1;
    if (b[m] < key) lo = m + 1; else hi = m;
  }
  return lo;
}

__global__ __launch_bounds__(256) void pool_final_kernel(const float* __restrict__ AGG,
                                                         const int* __restrict__ batch,
                                                         const float* __restrict__ Wl,
                                                         const float* __restrict__ bl,
                                                         float* __restrict__ out) {
  int g = blockIdx.x;
  int tid = threadIdx.x;
  int lane = tid & 63, w = tid >> 6;
  int start = lower_bound(batch, NN, g);
  int end = lower_bound(batch, NN, g + 1);

  const float2* AGG2 = reinterpret_cast<const float2*>(AGG);
  float2 acc = make_float2(0.f, 0.f);
  for (int n = start + w; n < end; n += 4) {
    float2 v = AGG2[(size_t)n * 64 + lane];
    acc.x += v.x; acc.y += v.y;
  }
  __shared__ float red[4][FD];
  red[w][lane * 2 + 0] = acc.x;
  red[w][lane * 2 + 1] = acc.y;
  __syncthreads();
  if (w == 0) {
    float px = red[0][lane * 2] + red[1][lane * 2] + red[2][lane * 2] + red[3][lane * 2];
    float py = red[0][lane * 2 + 1] + red[1][lane * 2 + 1] + red[2][lane * 2 + 1] + red[3][lane * 2 + 1];
    float inv = 1.0f / fmaxf((float)(end - start), 1.0f);
    px *= inv; py *= inv;
    float pc[NC];
    #pragma unroll
    for (int c = 0; c < NC; ++c)
      pc[c] = px * Wl[(2 * lane) * NC + c] + py * Wl[(2 * lane + 1) * NC + c];
    #pragma unroll
    for (int off = 32; off > 0; off >>= 1) {
      #pragma unroll
      for (int c = 0; c < NC; ++c) pc[c] += __shfl_down(pc[c], off, 64);
    }
    if (lane == 0) {
      #pragma unroll
      for (int c = 0; c < NC; ++c) out[g * NC + c] = pc[c] + bl[c];
    }
  }
}

// ---------------- launch ----------------

extern "C" void kernel_launch(void* const* d_in, const int* in_sizes, int n_in,
                              void* d_out, int out_size, void* d_ws, size_t ws_size,
                              hipStream_t stream) {
  const float* x       = (const float*)d_in[0];
  const int* ei        = (const int*)d_in[1];    // int32 on device
  const int* batch     = (const int*)d_in[2];    // int32 on device
  const float* W1 = (const float*)d_in[3];
  const float* b1 = (const float*)d_in[4];
  const float* W2 = (const float*)d_in[5];
  const float* b2 = (const float*)d_in[6];
  const float* W3 = (const float*)d_in[7];
  const float* b3 = (const float*)d_in[8];
  const float* Wl = (const float*)d_in[9];
  const float* bl = (const float*)d_in[10];
  float* out = (float*)d_out;

  char* ws = (char*)d_ws;
  size_t o = 0;
  auto alloc = [&](size_t bytes) {
    void* p = ws + o;
    o += bytes;
    o = (o + 255) & ~(size_t)255;
    return p;
  };
  int*   cnt    = (int*)  alloc((size_t)NN * 4);
  int*   offs   = (int*)  alloc((size_t)(NN + 1) * 4);
  int*   cursor = (int*)  alloc((size_t)NN * 4);
  float* dis    = (float*)alloc((size_t)NN * 4);
  int*   ssrc   = (int*)  alloc((size_t)NE * 4);
  float* scoef  = (float*)alloc((size_t)NE * 4);
  float* h      = (float*)alloc((size_t)NN * FD * 4);
  float* agg    = (float*)alloc((size_t)NN * FD * 4);
  int*   bsum   = (int*)  alloc((size_t)NBLK * 4);
  int*   bpre   = (int*)  alloc((size_t)NBLK * 4);

  zero_kernel<<<(NN + 255) / 256, 256, 0, stream>>>(cnt, NN);
  count_kernel<<<(NE + 255) / 256, 256, 0, stream>>>(ei, cnt);
  dis_kernel<<<(NN + 255) / 256, 256, 0, stream>>>(cnt, dis);
  scan_sum_kernel<<<NBLK, 256, 0, stream>>>(cnt, bsum);
  scan_bsum_kernel<<<1, 64, 0, stream>>>(bsum, bpre, offs);
  scan_write_kernel<<<NBLK, 256, 0, stream>>>(cnt, bpre, offs, cursor);
  fill_kernel<<<(NE + 255) / 256, 256, 0, stream>>>(ei, dis, cursor, ssrc, scoef);

  int gemmGrid = (NN + 63) / 64;
  int nodeGrid = (NN + 3) / 4;

  // layer 1
  gemm_kernel<<<gemmGrid, 256, 0, stream>>>(x, W1, h, 0);
  agg_edge_kernel<<<nodeGrid, 256, 0, stream>>>(offs, ssrc, scoef, h, dis, b1, agg);
  // layer 2
  gemm_kernel<<<gemmGrid, 256, 0, stream>>>(agg, W2, h, 1);
  agg_edge_kernel<<<nodeGrid, 256, 0, stream>>>(offs, ssrc, scoef, h, dis, b2, agg);
  // layer 3
  gemm_kernel<<<gemmGrid, 256, 0, stream>>>(agg, W3, h, 1);
  agg_edge_kernel<<<nodeGrid, 256, 0, stream>>>(offs, ssrc, scoef, h, dis, b3, agg);

  pool_final_kernel<<<NG, 256, 0, stream>>>(agg, batch, Wl, bl, out);
}

// Round 4
// 329.644 us; speedup vs baseline: 1.7362x; 1.2176x over previous
//
#include <hip/hip_runtime.h>

#define NN 50000
#define NE 800000
#define FD 128
#define NG 512
#define NC 10

#define SCAN_TILE 1024
#define NBLK ((NN + SCAN_TILE - 1) / SCAN_TILE)  // 49

// ---------------- bf16 helpers (manual, fp32 compute everywhere) ----------------

__device__ __forceinline__ float bf2f(unsigned short u) {
  return __uint_as_float(((unsigned int)u) << 16);
}
__device__ __forceinline__ unsigned short f2bf(float f) {
  unsigned int b = __float_as_uint(f);
  b += 0x7FFF + ((b >> 16) & 1);   // round-to-nearest-even
  return (unsigned short)(b >> 16);
}

// ---------------- setup: degree, dis, CSR build ----------------

__global__ __launch_bounds__(256) void zero_kernel(int* __restrict__ p, int n) {
  int i = blockIdx.x * 256 + threadIdx.x;
  if (i < n) p[i] = 0;
}

__global__ __launch_bounds__(256) void count_kernel(const int* __restrict__ ei,
                                                    int* __restrict__ cnt) {
  int e = blockIdx.x * 256 + threadIdx.x;
  if (e >= NE) return;
  atomicAdd(&cnt[ei[NE + e]], 1);
}

__global__ __launch_bounds__(256) void dis_kernel(const int* __restrict__ cnt,
                                                  float* __restrict__ dis) {
  int n = blockIdx.x * 256 + threadIdx.x;
  if (n >= NN) return;
  dis[n] = rsqrtf((float)cnt[n] + 1.0f);
}

// --- 3-phase multi-block exclusive scan over cnt[NN] ---

__global__ __launch_bounds__(256) void scan_sum_kernel(const int* __restrict__ cnt,
                                                       int* __restrict__ bsum) {
  __shared__ int red[256];
  int tid = threadIdx.x;
  int base = blockIdx.x * SCAN_TILE + tid * 4;
  int s = 0;
  #pragma unroll
  for (int i = 0; i < 4; ++i) {
    int idx = base + i;
    if (idx < NN) s += cnt[idx];
  }
  red[tid] = s;
  __syncthreads();
  #pragma unroll
  for (int off = 128; off > 0; off >>= 1) {
    if (tid < off) red[tid] += red[tid + off];
    __syncthreads();
  }
  if (tid == 0) bsum[blockIdx.x] = red[0];
}

__global__ __launch_bounds__(64) void scan_bsum_kernel(const int* __restrict__ bsum,
                                                       int* __restrict__ bpre,
                                                       int* __restrict__ offs) {
  int tid = threadIdx.x;
  int orig = (tid < NBLK) ? bsum[tid] : 0;
  int v = orig;
  #pragma unroll
  for (int off = 1; off < 64; off <<= 1) {
    int u = __shfl_up(v, off, 64);
    if (tid >= off) v += u;
  }
  if (tid < NBLK) bpre[tid] = v - orig;   // exclusive
  if (tid == NBLK - 1) offs[NN] = v;      // total == NE
}

__global__ __launch_bounds__(256) void scan_write_kernel(const int* __restrict__ cnt,
                                                         const int* __restrict__ bpre,
                                                         int* __restrict__ offs,
                                                         int* __restrict__ cursor) {
  __shared__ int lds[256];
  int tid = threadIdx.x;
  int base = blockIdx.x * SCAN_TILE + tid * 4;
  int v0 = 0, v1 = 0, v2 = 0, v3 = 0;
  if (base + 0 < NN) v0 = cnt[base + 0];
  if (base + 1 < NN) v1 = cnt[base + 1];
  if (base + 2 < NN) v2 = cnt[base + 2];
  if (base + 3 < NN) v3 = cnt[base + 3];
  int s = v0 + v1 + v2 + v3;
  lds[tid] = s;
  __syncthreads();
  #pragma unroll
  for (int off = 1; off < 256; off <<= 1) {
    int u = (tid >= off) ? lds[tid - off] : 0;
    __syncthreads();
    lds[tid] += u;
    __syncthreads();
  }
  int run = bpre[blockIdx.x] + lds[tid] - s;  // exclusive prefix
  if (base + 0 < NN) { offs[base + 0] = run; cursor[base + 0] = run; run += v0; }
  if (base + 1 < NN) { offs[base + 1] = run; cursor[base + 1] = run; run += v1; }
  if (base + 2 < NN) { offs[base + 2] = run; cursor[base + 2] = run; run += v2; }
  if (base + 3 < NN) { offs[base + 3] = run; cursor[base + 3] = run; run += v3; }
}

__global__ __launch_bounds__(256) void fill_kernel(const int* __restrict__ ei,
                                                   const float* __restrict__ dis,
                                                   int* __restrict__ cursor,
                                                   int* __restrict__ ssrc,
                                                   float* __restrict__ scoef) {
  int e = blockIdx.x * 256 + threadIdx.x;
  if (e >= NE) return;
  int s = ei[e];
  int d = ei[NE + e];
  int pos = atomicAdd(&cursor[d], 1);
  ssrc[pos] = s;
  scoef[pos] = dis[s] * dis[d];
}

// ---------------- GEMM: Hb(bf16) = act(A) @ W  (A: NN x 128 fp32, W: 128 x 128) ------

__device__ __forceinline__ void fma4(float4& acc, float s, const float4& w) {
  acc.x += s * w.x; acc.y += s * w.y; acc.z += s * w.z; acc.w += s * w.w;
}

#define SA_LDF4 33  // 132 floats per row (pad 4) -> 2-way bank conflict = free

__global__ __launch_bounds__(256) void gemm_kernel(const float* __restrict__ A,
                                                   const float* __restrict__ W,
                                                   unsigned short* __restrict__ Hb,
                                                   int applyRelu) {
  __shared__ float sA[64 * 132];   // 33.8 KB
  __shared__ float sW[128 * 64];   // 32 KB
  float4* sA4 = reinterpret_cast<float4*>(sA);
  float4* sW4 = reinterpret_cast<float4*>(sW);
  const float4* A4 = reinterpret_cast<const float4*>(A);
  const float4* W4 = reinterpret_cast<const float4*>(W);
  int tid = threadIdx.x;
  int rowBase = blockIdx.x * 64;

  for (int i = tid; i < 64 * 32; i += 256) {
    int r = i >> 5, c4 = i & 31;
    int gr = rowBase + r;
    float4 v = make_float4(0.f, 0.f, 0.f, 0.f);
    if (gr < NN) v = A4[gr * 32 + c4];
    if (applyRelu) {
      v.x = fmaxf(v.x, 0.f); v.y = fmaxf(v.y, 0.f);
      v.z = fmaxf(v.z, 0.f); v.w = fmaxf(v.w, 0.f);
    }
    sA4[r * SA_LDF4 + c4] = v;
  }

  int tc = tid & 15;
  int tr = tid >> 4;

  for (int half = 0; half < 2; ++half) {
    __syncthreads();
    int cb4 = half * 16;
    for (int i = tid; i < 128 * 16; i += 256) {
      int k = i >> 4, c4 = i & 15;
      sW4[i] = W4[k * 32 + cb4 + c4];
    }
    __syncthreads();

    float4 acc0 = make_float4(0,0,0,0), acc1 = make_float4(0,0,0,0);
    float4 acc2 = make_float4(0,0,0,0), acc3 = make_float4(0,0,0,0);
    #pragma unroll 4
    for (int kq = 0; kq < 32; ++kq) {
      float4 w0 = sW4[(kq * 4 + 0) * 16 + tc];
      float4 w1 = sW4[(kq * 4 + 1) * 16 + tc];
      float4 w2 = sW4[(kq * 4 + 2) * 16 + tc];
      float4 w3 = sW4[(kq * 4 + 3) * 16 + tc];
      float4 a;
      a = sA4[(tr * 4 + 0) * SA_LDF4 + kq];
      fma4(acc0, a.x, w0); fma4(acc0, a.y, w1); fma4(acc0, a.z, w2); fma4(acc0, a.w, w3);
      a = sA4[(tr * 4 + 1) * SA_LDF4 + kq];
      fma4(acc1, a.x, w0); fma4(acc1, a.y, w1); fma4(acc1, a.z, w2); fma4(acc1, a.w, w3);
      a = sA4[(tr * 4 + 2) * SA_LDF4 + kq];
      fma4(acc2, a.x, w0); fma4(acc2, a.y, w1); fma4(acc2, a.z, w2); fma4(acc2, a.w, w3);
      a = sA4[(tr * 4 + 3) * SA_LDF4 + kq];
      fma4(acc3, a.x, w0); fma4(acc3, a.y, w1); fma4(acc3, a.z, w2); fma4(acc3, a.w, w3);
    }
    int gr = rowBase + tr * 4;
    int cofs = (cb4 + tc) * 4;
    #pragma unroll
    for (int rr = 0; rr < 4; ++rr) {
      float4 acc = (rr == 0) ? acc0 : (rr == 1) ? acc1 : (rr == 2) ? acc2 : acc3;
      if (gr + rr < NN) {
        ushort4 o;
        o.x = f2bf(acc.x); o.y = f2bf(acc.y); o.z = f2bf(acc.z); o.w = f2bf(acc.w);
        *reinterpret_cast<ushort4*>(&Hb[(size_t)(gr + rr) * FD + cofs]) = o;
      }
    }
  }
}

// ---------------- fused aggregation (self-loop + bias + bf16 edge gather) ----------
// AGG[n][c] = b[c] + dis[n]^2 * H[n][c] + sum_{e: dst=n} coef_e * H[src_e][c]
// One wave per node; lanes 0-31 handle even edges, lanes 32-63 odd edges;
// each lane covers 4 channels (ushort4 = 8B loads); shfl_xor(32) combine.

__global__ __launch_bounds__(256) void agg_edge_kernel(const int* __restrict__ offs,
                                                       const int* __restrict__ ssrc,
                                                       const float* __restrict__ scoef,
                                                       const unsigned short* __restrict__ Hb,
                                                       const float* __restrict__ dis,
                                                       const float* __restrict__ b,
                                                       float* __restrict__ AGG) {
  int node = blockIdx.x * 4 + (threadIdx.x >> 6);
  if (node >= NN) return;
  node = __builtin_amdgcn_readfirstlane(node);  // wave-uniform -> scalar loads
  int lane = threadIdx.x & 63;
  int half = lane >> 5;        // 0: even edges, 1: odd edges
  int ch = (lane & 31) * 4;    // channel base for this lane
  int beg = offs[node], end = offs[node + 1];

  float4 accA, accB = make_float4(0.f, 0.f, 0.f, 0.f);
  {
    float d = dis[node];
    float d2 = d * d;
    if (half == 0) {
      float4 bb = reinterpret_cast<const float4*>(b)[lane & 31];
      ushort4 hn = *reinterpret_cast<const ushort4*>(&Hb[(size_t)node * FD + ch]);
      accA = make_float4(bb.x + d2 * bf2f(hn.x), bb.y + d2 * bf2f(hn.y),
                         bb.z + d2 * bf2f(hn.z), bb.w + d2 * bf2f(hn.w));
    } else {
      accA = make_float4(0.f, 0.f, 0.f, 0.f);
    }
  }

  int j = beg;
  for (; j + 3 < end; j += 4) {
    int s0 = ssrc[j], s1 = ssrc[j + 1], s2 = ssrc[j + 2], s3 = ssrc[j + 3];
    float c0 = scoef[j], c1 = scoef[j + 1], c2 = scoef[j + 2], c3 = scoef[j + 3];
    int sa = half ? s1 : s0;  float ca = half ? c1 : c0;
    int sb = half ? s3 : s2;  float cb = half ? c3 : c2;
    ushort4 ha = *reinterpret_cast<const ushort4*>(&Hb[(size_t)sa * FD + ch]);
    ushort4 hb = *reinterpret_cast<const ushort4*>(&Hb[(size_t)sb * FD + ch]);
    accA.x += ca * bf2f(ha.x); accA.y += ca * bf2f(ha.y);
    accA.z += ca * bf2f(ha.z); accA.w += ca * bf2f(ha.w);
    accB.x += cb * bf2f(hb.x); accB.y += cb * bf2f(hb.y);
    accB.z += cb * bf2f(hb.z); accB.w += cb * bf2f(hb.w);
  }
  for (; j < end; j += 2) {
    int s0 = ssrc[j];
    float c0 = scoef[j];
    int s1 = s0; float c1 = 0.f;
    if (j + 1 < end) { s1 = ssrc[j + 1]; c1 = scoef[j + 1]; }
    int sa = half ? s1 : s0;  float ca = half ? c1 : c0;
    ushort4 ha = *reinterpret_cast<const ushort4*>(&Hb[(size_t)sa * FD + ch]);
    accA.x += ca * bf2f(ha.x); accA.y += ca * bf2f(ha.y);
    accA.z += ca * bf2f(ha.z); accA.w += ca * bf2f(ha.w);
  }
  accA.x += accB.x; accA.y += accB.y; accA.z += accB.z; accA.w += accB.w;

  // combine the two half-wave partial sums
  accA.x += __shfl_xor(accA.x, 32, 64);
  accA.y += __shfl_xor(accA.y, 32, 64);
  accA.z += __shfl_xor(accA.z, 32, 64);
  accA.w += __shfl_xor(accA.w, 32, 64);

  if (half == 0) {
    reinterpret_cast<float4*>(AGG)[(size_t)node * 32 + (lane & 31)] = accA;
  }
}

// ---------------- fused pooling + classifier ----------------

__device__ __forceinline__ int lower_bound(const int* __restrict__ b, int n, int key) {
  int lo = 0, hi = n;
  while (lo < hi) {
    int m = (lo + hi) >> 1;
    if (b[m] < key) lo = m + 1; else hi = m;
  }
  return lo;
}

__global__ __launch_bounds__(256) void pool_final_kernel(const float* __restrict__ AGG,
                                                         const int* __restrict__ batch,
                                                         const float* __restrict__ Wl,
                                                         const float* __restrict__ bl,
                                                         float* __restrict__ out) {
  int g = blockIdx.x;
  int tid = threadIdx.x;
  int lane = tid & 63, w = tid >> 6;
  int start = lower_bound(batch, NN, g);
  int end = lower_bound(batch, NN, g + 1);

  const float2* AGG2 = reinterpret_cast<const float2*>(AGG);
  float2 acc = make_float2(0.f, 0.f);
  for (int n = start + w; n < end; n += 4) {
    float2 v = AGG2[(size_t)n * 64 + lane];
    acc.x += v.x; acc.y += v.y;
  }
  __shared__ float red[4][FD];
  red[w][lane * 2 + 0] = acc.x;
  red[w][lane * 2 + 1] = acc.y;
  __syncthreads();
  if (w == 0) {
    float px = red[0][lane * 2] + red[1][lane * 2] + red[2][lane * 2] + red[3][lane * 2];
    float py = red[0][lane * 2 + 1] + red[1][lane * 2 + 1] + red[2][lane * 2 + 1] + red[3][lane * 2 + 1];
    float inv = 1.0f / fmaxf((float)(end - start), 1.0f);
    px *= inv; py *= inv;
    float pc[NC];
    #pragma unroll
    for (int c = 0; c < NC; ++c)
      pc[c] = px * Wl[(2 * lane) * NC + c] + py * Wl[(2 * lane + 1) * NC + c];
    #pragma unroll
    for (int off = 32; off > 0; off >>= 1) {
      #pragma unroll
      for (int c = 0; c < NC; ++c) pc[c] += __shfl_down(pc[c], off, 64);
    }
    if (lane == 0) {
      #pragma unroll
      for (int c = 0; c < NC; ++c) out[g * NC + c] = pc[c] + bl[c];
    }
  }
}

// ---------------- launch ----------------

extern "C" void kernel_launch(void* const* d_in, const int* in_sizes, int n_in,
                              void* d_out, int out_size, void* d_ws, size_t ws_size,
                              hipStream_t stream) {
  const float* x       = (const float*)d_in[0];
  const int* ei        = (const int*)d_in[1];    // int32 on device
  const int* batch     = (const int*)d_in[2];    // int32 on device
  const float* W1 = (const float*)d_in[3];
  const float* b1 = (const float*)d_in[4];
  const float* W2 = (const float*)d_in[5];
  const float* b2 = (const float*)d_in[6];
  const float* W3 = (const float*)d_in[7];
  const float* b3 = (const float*)d_in[8];
  const float* Wl = (const float*)d_in[9];
  const float* bl = (const float*)d_in[10];
  float* out = (float*)d_out;

  char* ws = (char*)d_ws;
  size_t o = 0;
  auto alloc = [&](size_t bytes) {
    void* p = ws + o;
    o += bytes;
    o = (o + 255) & ~(size_t)255;
    return p;
  };
  int*   cnt    = (int*)  alloc((size_t)NN * 4);
  int*   offs   = (int*)  alloc((size_t)(NN + 1) * 4);
  int*   cursor = (int*)  alloc((size_t)NN * 4);
  float* dis    = (float*)alloc((size_t)NN * 4);
  int*   ssrc   = (int*)  alloc((size_t)NE * 4);
  float* scoef  = (float*)alloc((size_t)NE * 4);
  unsigned short* hb = (unsigned short*)alloc((size_t)NN * FD * 2);
  float* agg    = (float*)alloc((size_t)NN * FD * 4);
  int*   bsum   = (int*)  alloc((size_t)NBLK * 4);
  int*   bpre   = (int*)  alloc((size_t)NBLK * 4);

  zero_kernel<<<(NN + 255) / 256, 256, 0, stream>>>(cnt, NN);
  count_kernel<<<(NE + 255) / 256, 256, 0, stream>>>(ei, cnt);
  dis_kernel<<<(NN + 255) / 256, 256, 0, stream>>>(cnt, dis);
  scan_sum_kernel<<<NBLK, 256, 0, stream>>>(cnt, bsum);
  scan_bsum_kernel<<<1, 64, 0, stream>>>(bsum, bpre, offs);
  scan_write_kernel<<<NBLK, 256, 0, stream>>>(cnt, bpre, offs, cursor);
  fill_kernel<<<(NE + 255) / 256, 256, 0, stream>>>(ei, dis, cursor, ssrc, scoef);

  int gemmGrid = (NN + 63) / 64;
  int nodeGrid = (NN + 3) / 4;

  // layer 1
  gemm_kernel<<<gemmGrid, 256, 0, stream>>>(x, W1, hb, 0);
  agg_edge_kernel<<<nodeGrid, 256, 0, stream>>>(offs, ssrc, scoef, hb, dis, b1, agg);
  // layer 2
  gemm_kernel<<<gemmGrid, 256, 0, stream>>>(agg, W2, hb, 1);
  agg_edge_kernel<<<nodeGrid, 256, 0, stream>>>(offs, ssrc, scoef, hb, dis, b2, agg);
  // layer 3
  gemm_kernel<<<gemmGrid, 256, 0, stream>>>(agg, W3, hb, 1);
  agg_edge_kernel<<<nodeGrid, 256, 0, stream>>>(offs, ssrc, scoef, hb, dis, b3, agg);

  pool_final_kernel<<<NG, 256, 0, stream>>>(agg, batch, Wl, bl, out);
}

// Round 5
// 301.745 us; speedup vs baseline: 1.8967x; 1.0925x over previous
//
#include <hip/hip_runtime.h>

#define NN 50000
#define NE 800000
#define FD 128
#define NG 512
#define NC 10

#define SCAN_TILE 1024
#define NBLK ((NN + SCAN_TILE - 1) / SCAN_TILE)  // 49

// bucketed CSR build
#define NBUCK 98            // ceil(50000/512)
#define BSHIFT 9            // 512 nodes per bucket
#define BSTRIDE 10240       // slots per bucket region (mean 8192, sd ~90)
#define P1_EPB 4096         // edges per pass1 block
#define P1_BLOCKS ((NE + P1_EPB - 1) / P1_EPB)  // 196

// ---------------- bf16 helpers ----------------

__device__ __forceinline__ float bf2f(unsigned short u) {
  return __uint_as_float(((unsigned int)u) << 16);
}
__device__ __forceinline__ unsigned short f2bf(float f) {
  unsigned int b = __float_as_uint(f);
  b += 0x7FFF + ((b >> 16) & 1);   // round-to-nearest-even
  return (unsigned short)(b >> 16);
}

// ---------------- setup ----------------

__global__ __launch_bounds__(256) void init_kernel(int* __restrict__ cnt,
                                                   int* __restrict__ gcursor) {
  int i = blockIdx.x * 256 + threadIdx.x;
  if (i < NN) cnt[i] = 0;
  if (i < NBUCK) gcursor[i] = i * BSTRIDE;
}

// pass1: bucket-scatter packed (src16|dst16) records with per-block LDS grouping;
// fused per-node degree count.
__global__ __launch_bounds__(1024) void pass1_kernel(const int* __restrict__ ei,
                                                     int* __restrict__ cnt,
                                                     int* __restrict__ gcursor,
                                                     unsigned int* __restrict__ bucketBuf) {
  __shared__ unsigned int recs[P1_EPB];
  __shared__ unsigned int grp[P1_EPB];
  __shared__ int bh[NBUCK];
  __shared__ int boff[NBUCK];
  __shared__ int bcur[NBUCK];
  __shared__ int gbase[NBUCK];

  int tid = threadIdx.x;
  int e0 = blockIdx.x * P1_EPB;
  int ne = NE - e0; if (ne > P1_EPB) ne = P1_EPB;

  if (tid < NBUCK) bh[tid] = 0;
  __syncthreads();

  for (int i = tid; i < ne; i += 1024) {
    int s = ei[e0 + i];
    int d = ei[NE + e0 + i];
    atomicAdd(&cnt[d], 1);
    atomicAdd(&bh[d >> BSHIFT], 1);
    recs[i] = (unsigned int)s | ((unsigned int)d << 16);
  }
  __syncthreads();

  if (tid == 0) {
    int r = 0;
    for (int b = 0; b < NBUCK; ++b) { boff[b] = r; r += bh[b]; }
  }
  __syncthreads();
  if (tid < NBUCK) {
    bcur[tid] = boff[tid];
    gbase[tid] = (bh[tid] > 0) ? atomicAdd(&gcursor[tid], bh[tid]) : 0;
  }
  __syncthreads();

  for (int i = tid; i < ne; i += 1024) {
    unsigned int r = recs[i];
    int b = (int)(r >> (16 + BSHIFT));
    int p = atomicAdd(&bcur[b], 1);
    grp[p] = r;
  }
  __syncthreads();

  for (int s = tid; s < ne; s += 1024) {
    // largest b with boff[b] <= s
    int lo = 0, hi = NBUCK - 1;
    while (lo < hi) { int m = (lo + hi + 1) >> 1; if (boff[m] <= s) lo = m; else hi = m - 1; }
    bucketBuf[gbase[lo] + (s - boff[lo])] = grp[s];
  }
}

__global__ __launch_bounds__(256) void dis_kernel(const int* __restrict__ cnt,
                                                  float* __restrict__ dis) {
  int n = blockIdx.x * 256 + threadIdx.x;
  if (n >= NN) return;
  dis[n] = rsqrtf((float)cnt[n] + 1.0f);
}

// --- 3-phase multi-block exclusive scan over cnt[NN] ---

__global__ __launch_bounds__(256) void scan_sum_kernel(const int* __restrict__ cnt,
                                                       int* __restrict__ bsum) {
  __shared__ int red[256];
  int tid = threadIdx.x;
  int base = blockIdx.x * SCAN_TILE + tid * 4;
  int s = 0;
  #pragma unroll
  for (int i = 0; i < 4; ++i) {
    int idx = base + i;
    if (idx < NN) s += cnt[idx];
  }
  red[tid] = s;
  __syncthreads();
  #pragma unroll
  for (int off = 128; off > 0; off >>= 1) {
    if (tid < off) red[tid] += red[tid + off];
    __syncthreads();
  }
  if (tid == 0) bsum[blockIdx.x] = red[0];
}

__global__ __launch_bounds__(64) void scan_bsum_kernel(const int* __restrict__ bsum,
                                                       int* __restrict__ bpre,
                                                       int* __restrict__ offs) {
  int tid = threadIdx.x;
  int orig = (tid < NBLK) ? bsum[tid] : 0;
  int v = orig;
  #pragma unroll
  for (int off = 1; off < 64; off <<= 1) {
    int u = __shfl_up(v, off, 64);
    if (tid >= off) v += u;
  }
  if (tid < NBLK) bpre[tid] = v - orig;   // exclusive
  if (tid == NBLK - 1) offs[NN] = v;      // total == NE
}

__global__ __launch_bounds__(256) void scan_write_kernel(const int* __restrict__ cnt,
                                                         const int* __restrict__ bpre,
                                                         int* __restrict__ offs) {
  __shared__ int lds[256];
  int tid = threadIdx.x;
  int base = blockIdx.x * SCAN_TILE + tid * 4;
  int v0 = 0, v1 = 0, v2 = 0, v3 = 0;
  if (base + 0 < NN) v0 = cnt[base + 0];
  if (base + 1 < NN) v1 = cnt[base + 1];
  if (base + 2 < NN) v2 = cnt[base + 2];
  if (base + 3 < NN) v3 = cnt[base + 3];
  int s = v0 + v1 + v2 + v3;
  lds[tid] = s;
  __syncthreads();
  #pragma unroll
  for (int off = 1; off < 256; off <<= 1) {
    int u = (tid >= off) ? lds[tid - off] : 0;
    __syncthreads();
    lds[tid] += u;
    __syncthreads();
  }
  int run = bpre[blockIdx.x] + lds[tid] - s;  // exclusive prefix
  if (base + 0 < NN) { offs[base + 0] = run; run += v0; }
  if (base + 1 < NN) { offs[base + 1] = run; run += v1; }
  if (base + 2 < NN) { offs[base + 2] = run; run += v2; }
  if (base + 3 < NN) { offs[base + 3] = run; run += v3; }
}

// pass2: per-bucket dst-sort in LDS, emit u16 src list coalesced.
__global__ __launch_bounds__(1024) void pass2_kernel(const unsigned int* __restrict__ bucketBuf,
                                                     const int* __restrict__ offs,
                                                     unsigned short* __restrict__ csr) {
  __shared__ unsigned int raw[BSTRIDE];      // 40 KB
  __shared__ unsigned short sorted[BSTRIDE]; // 20 KB
  __shared__ int h[512], pos[512], cur[512];

  int b = blockIdx.x;
  int tid = threadIdx.x;
  int nStart = b << BSHIFT;
  int nEnd = nStart + 512; if (nEnd > NN) nEnd = NN;
  int eStart = offs[nStart], eEnd = offs[nEnd];
  int cnt = eEnd - eStart;
  if (cnt > BSTRIDE) cnt = BSTRIDE;  // impossible for this input; OOB guard

  for (int i = tid; i < cnt; i += 1024) raw[i] = bucketBuf[(size_t)b * BSTRIDE + i];
  if (tid < 512) h[tid] = 0;
  __syncthreads();

  for (int i = tid; i < cnt; i += 1024) atomicAdd(&h[(raw[i] >> 16) - nStart], 1);
  __syncthreads();

  if (tid < 512) pos[tid] = h[tid];
  __syncthreads();
  #pragma unroll
  for (int off = 1; off < 512; off <<= 1) {
    int v = 0;
    if (tid < 512 && tid >= off) v = pos[tid - off];
    __syncthreads();
    if (tid < 512) pos[tid] += v;
    __syncthreads();
  }
  if (tid < 512) cur[tid] = pos[tid] - h[tid];  // exclusive
  __syncthreads();

  for (int i = tid; i < cnt; i += 1024) {
    unsigned int r = raw[i];
    int d = (int)(r >> 16) - nStart;
    int p = atomicAdd(&cur[d], 1);
    sorted[p] = (unsigned short)(r & 0xFFFFu);
  }
  __syncthreads();

  for (int i = tid; i < cnt; i += 1024) csr[eStart + i] = sorted[i];
}

// ---------------- GEMM: Hb(bf16) = act(A) @ W ----------------

__device__ __forceinline__ void fma4(float4& acc, float s, const float4& w) {
  acc.x += s * w.x; acc.y += s * w.y; acc.z += s * w.z; acc.w += s * w.w;
}

#define SA_LDF4 33  // 132 floats per row (pad 4) -> 2-way bank conflict = free

__global__ __launch_bounds__(256) void gemm_kernel(const float* __restrict__ A,
                                                   const float* __restrict__ W,
                                                   unsigned short* __restrict__ Hb,
                                                   int applyRelu) {
  __shared__ float sA[64 * 132];
  __shared__ float sW[128 * 64];
  float4* sA4 = reinterpret_cast<float4*>(sA);
  float4* sW4 = reinterpret_cast<float4*>(sW);
  const float4* A4 = reinterpret_cast<const float4*>(A);
  const float4* W4 = reinterpret_cast<const float4*>(W);
  int tid = threadIdx.x;
  int rowBase = blockIdx.x * 64;

  for (int i = tid; i < 64 * 32; i += 256) {
    int r = i >> 5, c4 = i & 31;
    int gr = rowBase + r;
    float4 v = make_float4(0.f, 0.f, 0.f, 0.f);
    if (gr < NN) v = A4[gr * 32 + c4];
    if (applyRelu) {
      v.x = fmaxf(v.x, 0.f); v.y = fmaxf(v.y, 0.f);
      v.z = fmaxf(v.z, 0.f); v.w = fmaxf(v.w, 0.f);
    }
    sA4[r * SA_LDF4 + c4] = v;
  }

  int tc = tid & 15;
  int tr = tid >> 4;

  for (int half = 0; half < 2; ++half) {
    __syncthreads();
    int cb4 = half * 16;
    for (int i = tid; i < 128 * 16; i += 256) {
      int k = i >> 4, c4 = i & 15;
      sW4[i] = W4[k * 32 + cb4 + c4];
    }
    __syncthreads();

    float4 acc0 = make_float4(0,0,0,0), acc1 = make_float4(0,0,0,0);
    float4 acc2 = make_float4(0,0,0,0), acc3 = make_float4(0,0,0,0);
    #pragma unroll 4
    for (int kq = 0; kq < 32; ++kq) {
      float4 w0 = sW4[(kq * 4 + 0) * 16 + tc];
      float4 w1 = sW4[(kq * 4 + 1) * 16 + tc];
      float4 w2 = sW4[(kq * 4 + 2) * 16 + tc];
      float4 w3 = sW4[(kq * 4 + 3) * 16 + tc];
      float4 a;
      a = sA4[(tr * 4 + 0) * SA_LDF4 + kq];
      fma4(acc0, a.x, w0); fma4(acc0, a.y, w1); fma4(acc0, a.z, w2); fma4(acc0, a.w, w3);
      a = sA4[(tr * 4 + 1) * SA_LDF4 + kq];
      fma4(acc1, a.x, w0); fma4(acc1, a.y, w1); fma4(acc1, a.z, w2); fma4(acc1, a.w, w3);
      a = sA4[(tr * 4 + 2) * SA_LDF4 + kq];
      fma4(acc2, a.x, w0); fma4(acc2, a.y, w1); fma4(acc2, a.z, w2); fma4(acc2, a.w, w3);
      a = sA4[(tr * 4 + 3) * SA_LDF4 + kq];
      fma4(acc3, a.x, w0); fma4(acc3, a.y, w1); fma4(acc3, a.z, w2); fma4(acc3, a.w, w3);
    }
    int gr = rowBase + tr * 4;
    int cofs = (cb4 + tc) * 4;
    #pragma unroll
    for (int rr = 0; rr < 4; ++rr) {
      float4 acc = (rr == 0) ? acc0 : (rr == 1) ? acc1 : (rr == 2) ? acc2 : acc3;
      if (gr + rr < NN) {
        ushort4 o;
        o.x = f2bf(acc.x); o.y = f2bf(acc.y); o.z = f2bf(acc.z); o.w = f2bf(acc.w);
        *reinterpret_cast<ushort4*>(&Hb[(size_t)(gr + rr) * FD + cofs]) = o;
      }
    }
  }
}

// ---------------- fused aggregation ----------------
// AGG[n][c] = b[c] + dis[n]^2 * H[n][c] + sum_e dis[src_e]*dis[n] * H[src_e][c]
// Wave per node; half-waves take alternate edges; 8-edge unroll (4 loads in
// flight per lane); u16 CSR; coef recomputed from dis (exact same floats).

__global__ __launch_bounds__(256) void agg_edge_kernel(const int* __restrict__ offs,
                                                       const unsigned short* __restrict__ csr,
                                                       const float* __restrict__ dis,
                                                       const unsigned short* __restrict__ Hb,
                                                       const float* __restrict__ b,
                                                       float* __restrict__ AGG) {
  int node = blockIdx.x * 4 + (threadIdx.x >> 6);
  if (node >= NN) return;
  node = __builtin_amdgcn_readfirstlane(node);
  int lane = threadIdx.x & 63;
  int half = lane >> 5;
  int ch = (lane & 31) * 4;
  int beg = offs[node], end = offs[node + 1];
  float disn = dis[node];

  float4 accA, accB = make_float4(0.f, 0.f, 0.f, 0.f);
  {
    float d2 = disn * disn;
    if (half == 0) {
      float4 bb = reinterpret_cast<const float4*>(b)[lane & 31];
      ushort4 hn = *reinterpret_cast<const ushort4*>(&Hb[(size_t)node * FD + ch]);
      accA = make_float4(bb.x + d2 * bf2f(hn.x), bb.y + d2 * bf2f(hn.y),
                         bb.z + d2 * bf2f(hn.z), bb.w + d2 * bf2f(hn.w));
    } else {
      accA = make_float4(0.f, 0.f, 0.f, 0.f);
    }
  }

  int j = beg;
  for (; j + 7 < end; j += 8) {
    int s0 = csr[j + 0 + half];
    int s1 = csr[j + 2 + half];
    int s2 = csr[j + 4 + half];
    int s3 = csr[j + 6 + half];
    float c0 = dis[s0] * disn;
    float c1 = dis[s1] * disn;
    float c2 = dis[s2] * disn;
    float c3 = dis[s3] * disn;
    ushort4 h0 = *reinterpret_cast<const ushort4*>(&Hb[(size_t)s0 * FD + ch]);
    ushort4 h1 = *reinterpret_cast<const ushort4*>(&Hb[(size_t)s1 * FD + ch]);
    ushort4 h2 = *reinterpret_cast<const ushort4*>(&Hb[(size_t)s2 * FD + ch]);
    ushort4 h3 = *reinterpret_cast<const ushort4*>(&Hb[(size_t)s3 * FD + ch]);
    accA.x += c0 * bf2f(h0.x); accA.y += c0 * bf2f(h0.y);
    accA.z += c0 * bf2f(h0.z); accA.w += c0 * bf2f(h0.w);
    accB.x += c1 * bf2f(h1.x); accB.y += c1 * bf2f(h1.y);
    accB.z += c1 * bf2f(h1.z); accB.w += c1 * bf2f(h1.w);
    accA.x += c2 * bf2f(h2.x); accA.y += c2 * bf2f(h2.y);
    accA.z += c2 * bf2f(h2.z); accA.w += c2 * bf2f(h2.w);
    accB.x += c3 * bf2f(h3.x); accB.y += c3 * bf2f(h3.y);
    accB.z += c3 * bf2f(h3.z); accB.w += c3 * bf2f(h3.w);
  }
  for (; j < end; j += 2) {
    int s0 = csr[j];
    float c0 = dis[s0] * disn;
    int s1 = s0; float c1 = 0.f;
    if (j + 1 < end) { s1 = csr[j + 1]; c1 = dis[s1] * disn; }
    int sa = half ? s1 : s0;  float ca = half ? c1 : c0;
    ushort4 ha = *reinterpret_cast<const ushort4*>(&Hb[(size_t)sa * FD + ch]);
    accA.x += ca * bf2f(ha.x); accA.y += ca * bf2f(ha.y);
    accA.z += ca * bf2f(ha.z); accA.w += ca * bf2f(ha.w);
  }
  accA.x += accB.x; accA.y += accB.y; accA.z += accB.z; accA.w += accB.w;

  accA.x += __shfl_xor(accA.x, 32, 64);
  accA.y += __shfl_xor(accA.y, 32, 64);
  accA.z += __shfl_xor(accA.z, 32, 64);
  accA.w += __shfl_xor(accA.w, 32, 64);

  if (half == 0) {
    reinterpret_cast<float4*>(AGG)[(size_t)node * 32 + (lane & 31)] = accA;
  }
}

// ---------------- fused pooling + classifier ----------------

__device__ __forceinline__ int lower_bound(const int* __restrict__ b, int n, int key) {
  int lo = 0, hi = n;
  while (lo < hi) {
    int m = (lo + hi) >> 1;
    if (b[m] < key) lo = m + 1; else hi = m;
  }
  return lo;
}

__global__ __launch_bounds__(256) void pool_final_kernel(const float* __restrict__ AGG,
                                                         const int* __restrict__ batch,
                                                         const float* __restrict__ Wl,
                                                         const float* __restrict__ bl,
                                                         float* __restrict__ out) {
  int g = blockIdx.x;
  int tid = threadIdx.x;
  int lane = tid & 63, w = tid >> 6;
  int start = lower_bound(batch, NN, g);
  int end = lower_bound(batch, NN, g + 1);

  const float2* AGG2 = reinterpret_cast<const float2*>(AGG);
  float2 acc = make_float2(0.f, 0.f);
  for (int n = start + w; n < end; n += 4) {
    float2 v = AGG2[(size_t)n * 64 + lane];
    acc.x += v.x; acc.y += v.y;
  }
  __shared__ float red[4][FD];
  red[w][lane * 2 + 0] = acc.x;
  red[w][lane * 2 + 1] = acc.y;
  __syncthreads();
  if (w == 0) {
    float px = red[0][lane * 2] + red[1][lane * 2] + red[2][lane * 2] + red[3][lane * 2];
    float py = red[0][lane * 2 + 1] + red[1][lane * 2 + 1] + red[2][lane * 2 + 1] + red[3][lane * 2 + 1];
    float inv = 1.0f / fmaxf((float)(end - start), 1.0f);
    px *= inv; py *= inv;
    float pc[NC];
    #pragma unroll
    for (int c = 0; c < NC; ++c)
      pc[c] = px * Wl[(2 * lane) * NC + c] + py * Wl[(2 * lane + 1) * NC + c];
    #pragma unroll
    for (int off = 32; off > 0; off >>= 1) {
      #pragma unroll
      for (int c = 0; c < NC; ++c) pc[c] += __shfl_down(pc[c], off, 64);
    }
    if (lane == 0) {
      #pragma unroll
      for (int c = 0; c < NC; ++c) out[g * NC + c] = pc[c] + bl[c];
    }
  }
}

// ---------------- launch ----------------

extern "C" void kernel_launch(void* const* d_in, const int* in_sizes, int n_in,
                              void* d_out, int out_size, void* d_ws, size_t ws_size,
                              hipStream_t stream) {
  const float* x       = (const float*)d_in[0];
  const int* ei        = (const int*)d_in[1];    // int32 on device
  const int* batch     = (const int*)d_in[2];    // int32 on device
  const float* W1 = (const float*)d_in[3];
  const float* b1 = (const float*)d_in[4];
  const float* W2 = (const float*)d_in[5];
  const float* b2 = (const float*)d_in[6];
  const float* W3 = (const float*)d_in[7];
  const float* b3 = (const float*)d_in[8];
  const float* Wl = (const float*)d_in[9];
  const float* bl = (const float*)d_in[10];
  float* out = (float*)d_out;

  char* ws = (char*)d_ws;
  size_t o = 0;
  auto alloc = [&](size_t bytes) {
    void* p = ws + o;
    o += bytes;
    o = (o + 255) & ~(size_t)255;
    return p;
  };
  int*   cnt    = (int*)  alloc((size_t)NN * 4);
  int*   offs   = (int*)  alloc((size_t)(NN + 1) * 4);
  float* dis    = (float*)alloc((size_t)NN * 4);
  int*   gcur   = (int*)  alloc((size_t)NBUCK * 4);
  unsigned int* bucketBuf = (unsigned int*)alloc((size_t)NBUCK * BSTRIDE * 4);
  unsigned short* csr = (unsigned short*)alloc((size_t)NE * 2);
  unsigned short* hb  = (unsigned short*)alloc((size_t)NN * FD * 2);
  float* agg    = (float*)alloc((size_t)NN * FD * 4);
  int*   bsum   = (int*)  alloc((size_t)NBLK * 4);
  int*   bpre   = (int*)  alloc((size_t)NBLK * 4);

  init_kernel<<<(NN + 255) / 256, 256, 0, stream>>>(cnt, gcur);
  pass1_kernel<<<P1_BLOCKS, 1024, 0, stream>>>(ei, cnt, gcur, bucketBuf);
  dis_kernel<<<(NN + 255) / 256, 256, 0, stream>>>(cnt, dis);
  scan_sum_kernel<<<NBLK, 256, 0, stream>>>(cnt, bsum);
  scan_bsum_kernel<<<1, 64, 0, stream>>>(bsum, bpre, offs);
  scan_write_kernel<<<NBLK, 256, 0, stream>>>(cnt, bpre, offs);
  pass2_kernel<<<NBUCK, 1024, 0, stream>>>(bucketBuf, offs, csr);

  int gemmGrid = (NN + 63) / 64;
  int nodeGrid = (NN + 3) / 4;

  // layer 1
  gemm_kernel<<<gemmGrid, 256, 0, stream>>>(x, W1, hb, 0);
  agg_edge_kernel<<<nodeGrid, 256, 0, stream>>>(offs, csr, dis, hb, b1, agg);
  // layer 2
  gemm_kernel<<<gemmGrid, 256, 0, stream>>>(agg, W2, hb, 1);
  agg_edge_kernel<<<nodeGrid, 256, 0, stream>>>(offs, csr, dis, hb, b2, agg);
  // layer 3
  gemm_kernel<<<gemmGrid, 256, 0, stream>>>(agg, W3, hb, 1);
  agg_edge_kernel<<<nodeGrid, 256, 0, stream>>>(offs, csr, dis, hb, b3, agg);

  pool_final_kernel<<<NG, 256, 0, stream>>>(agg, batch, Wl, bl, out);
}

// Round 6
// 205.623 us; speedup vs baseline: 2.7834x; 1.4675x over previous
//
#include <hip/hip_runtime.h>

#define NN 50000
#define NE 800000
#define FD 128
#define NG 512
#define NC 10

// bucketed CSR build
#define NBUCK 98            // ceil(50000/512)
#define BSHIFT 9            // 512 nodes per bucket
#define BSTRIDE 10240       // slots per bucket region (mean 8192, sd ~90)
#define P1_EPB 4096         // edges per pass1 block
#define P1_BLOCKS ((NE + P1_EPB - 1) / P1_EPB)  // 196

typedef __attribute__((ext_vector_type(8))) short bf16x8;
typedef __attribute__((ext_vector_type(4))) float f32x4;

// ---------------- bf16 helpers ----------------

__device__ __forceinline__ float bf2f(unsigned short u) {
  return __uint_as_float(((unsigned int)u) << 16);
}
__device__ __forceinline__ unsigned short f2bf(float f) {
  unsigned int b = __float_as_uint(f);
  b += 0x7FFF + ((b >> 16) & 1);   // round-to-nearest-even
  return (unsigned short)(b >> 16);
}

// ---------------- setup ----------------

__global__ __launch_bounds__(128) void init_kernel(int* __restrict__ gcursor) {
  int i = threadIdx.x;
  if (i < NBUCK) gcursor[i] = i * BSTRIDE;
}

// pass1: bucket-scatter packed (src16|dst16) records with per-block LDS grouping.
// NO per-node atomics (degree is derived in pass2).
__global__ __launch_bounds__(1024) void pass1_kernel(const int* __restrict__ ei,
                                                     int* __restrict__ gcursor,
                                                     unsigned int* __restrict__ bucketBuf) {
  __shared__ unsigned int recs[P1_EPB];
  __shared__ unsigned int grp[P1_EPB];
  __shared__ int bh[NBUCK];
  __shared__ int boff[NBUCK];
  __shared__ int bcur[NBUCK];
  __shared__ int gbase[NBUCK];
  __shared__ int bscan[128];

  int tid = threadIdx.x;
  int e0 = blockIdx.x * P1_EPB;
  int ne = NE - e0; if (ne > P1_EPB) ne = P1_EPB;

  if (tid < NBUCK) bh[tid] = 0;
  __syncthreads();

  for (int i = tid; i < ne; i += 1024) {
    int s = ei[e0 + i];
    int d = ei[NE + e0 + i];
    atomicAdd(&bh[d >> BSHIFT], 1);
    recs[i] = (unsigned int)s | ((unsigned int)d << 16);
  }
  __syncthreads();

  // 128-thread LDS scan over 98 bucket counts
  if (tid < 128) bscan[tid] = (tid < NBUCK) ? bh[tid] : 0;
  __syncthreads();
  for (int off = 1; off < 128; off <<= 1) {
    int v = 0;
    if (tid < 128 && tid >= off) v = bscan[tid - off];
    __syncthreads();
    if (tid < 128) bscan[tid] += v;
    __syncthreads();
  }
  if (tid < NBUCK) {
    boff[tid] = bscan[tid] - bh[tid];
    bcur[tid] = bscan[tid] - bh[tid];
    gbase[tid] = (bh[tid] > 0) ? atomicAdd(&gcursor[tid], bh[tid]) : 0;
  }
  __syncthreads();

  for (int i = tid; i < ne; i += 1024) {
    unsigned int r = recs[i];
    int b = (int)(r >> (16 + BSHIFT));
    int p = atomicAdd(&bcur[b], 1);
    grp[p] = r;
  }
  __syncthreads();

  for (int s = tid; s < ne; s += 1024) {
    // largest b with boff[b] <= s
    int lo = 0, hi = NBUCK - 1;
    while (lo < hi) { int m = (lo + hi + 1) >> 1; if (boff[m] <= s) lo = m; else hi = m - 1; }
    bucketBuf[gbase[lo] + (s - boff[lo])] = grp[s];
  }
}

// exclusive scan of 98 bucket totals -> bbase
__global__ __launch_bounds__(128) void bucket_scan_kernel(const int* __restrict__ gcur,
                                                          int* __restrict__ bbase) {
  __shared__ int s[128];
  int tid = threadIdx.x;
  int c = (tid < NBUCK) ? (gcur[tid] - tid * BSTRIDE) : 0;
  s[tid] = c;
  __syncthreads();
  for (int off = 1; off < 128; off <<= 1) {
    int v = (tid >= off) ? s[tid - off] : 0;
    __syncthreads();
    s[tid] += v;
    __syncthreads();
  }
  if (tid < NBUCK) bbase[tid] = s[tid] - c;
}

// pass2: per-bucket dst-sort in LDS; derives degree -> dis, offs; emits u16 CSR.
__global__ __launch_bounds__(1024) void pass2_kernel(const unsigned int* __restrict__ bucketBuf,
                                                     const int* __restrict__ gcur,
                                                     const int* __restrict__ bbase,
                                                     int* __restrict__ offs,
                                                     float* __restrict__ dis,
                                                     unsigned short* __restrict__ csr) {
  __shared__ unsigned int raw[BSTRIDE];      // 40 KB
  __shared__ unsigned short sorted[BSTRIDE]; // 20 KB
  __shared__ int h[512], pos[512], cur[512];

  int b = blockIdx.x;
  int tid = threadIdx.x;
  int nStart = b << BSHIFT;
  int cnt = gcur[b] - b * BSTRIDE;
  if (cnt > BSTRIDE) cnt = BSTRIDE;  // OOB guard (statistically impossible)
  int eStart = bbase[b];

  for (int i = tid; i < cnt; i += 1024) raw[i] = bucketBuf[(size_t)b * BSTRIDE + i];
  if (tid < 512) h[tid] = 0;
  __syncthreads();

  for (int i = tid; i < cnt; i += 1024) atomicAdd(&h[(raw[i] >> 16) - nStart], 1);
  __syncthreads();

  if (tid < 512) pos[tid] = h[tid];
  __syncthreads();
  #pragma unroll
  for (int off = 1; off < 512; off <<= 1) {
    int v = 0;
    if (tid < 512 && tid >= off) v = pos[tid - off];
    __syncthreads();
    if (tid < 512) pos[tid] += v;
    __syncthreads();
  }
  if (tid < 512) {
    int ex = pos[tid] - h[tid];   // exclusive prefix
    cur[tid] = ex;
    int n = nStart + tid;
    if (n < NN) {
      offs[n] = eStart + ex;
      dis[n] = rsqrtf((float)h[tid] + 1.0f);
    }
  }
  if (b == NBUCK - 1 && tid == 0) offs[NN] = eStart + cnt;
  __syncthreads();

  for (int i = tid; i < cnt; i += 1024) {
    unsigned int r = raw[i];
    int d = (int)(r >> 16) - nStart;
    int p = atomicAdd(&cur[d], 1);
    sorted[p] = (unsigned short)(r & 0xFFFFu);
  }
  __syncthreads();

  for (int i = tid; i < cnt; i += 1024) csr[eStart + i] = sorted[i];
}

// ---------------- W fragment prep: split to bf16 hi/lo in MFMA lane order ----------
// wf layout: [ct(8)][ks(4)][plane(2: hi,lo)][lane(64)][j(8)] bf16
// element (k, c): k = ks*32 + (lane>>4)*8 + j ; c = ct*16 + (lane&15)

__global__ __launch_bounds__(256) void prep_w_kernel(const float* __restrict__ W,
                                                     unsigned short* __restrict__ wf) {
  int i = blockIdx.x * 256 + threadIdx.x;  // 0..16383
  if (i >= 16384) return;
  int j = i & 7, l = (i >> 3) & 63, ks = (i >> 9) & 3, ct = i >> 11;
  int k = ks * 32 + (l >> 4) * 8 + j;
  int c = ct * 16 + (l & 15);
  float w = W[k * 128 + c];
  unsigned int bb = __float_as_uint(w);
  unsigned int bh = bb & 0xFFFF0000u;
  float r = w - __uint_as_float(bh);    // exact (hi is a bit-truncation of w)
  int base = (((ct * 4 + ks) * 2 + 0) * 64 + l) * 8 + j;
  wf[base] = (unsigned short)(bh >> 16);
  wf[base + 512] = f2bf(r);             // lo plane: +64*8 shorts
}

// ---------------- MFMA GEMM: Hb(bf16) = act(A) @ W via 3-term bf16 split ----------
// block = 256 thr = 4 waves, 64 rows (16 rows/wave), 128 cols.
// W fragments (hi+lo, 64KB) staged to LDS once; A streams global->reg.

__global__ __launch_bounds__(256) void gemm_mfma_kernel(const float* __restrict__ A,
                                                        const unsigned short* __restrict__ wf,
                                                        unsigned short* __restrict__ Hb,
                                                        int applyRelu) {
  __shared__ unsigned short ldsW[32768];  // 64 KB
  int tid = threadIdx.x;
  {
    const uint4* src = reinterpret_cast<const uint4*>(wf);
    uint4* dst = reinterpret_cast<uint4*>(ldsW);
    #pragma unroll
    for (int i = 0; i < 16; ++i) dst[tid + i * 256] = src[tid + i * 256];
  }
  __syncthreads();

  int w = tid >> 6, lane = tid & 63;
  int rowbase = blockIdx.x * 64 + w * 16;
  int arow = rowbase + (lane & 15);
  if (arow >= NN) arow = 0;               // clamp; stores guarded
  int kgrp = lane >> 4;

  f32x4 acc[8];
  #pragma unroll
  for (int ct = 0; ct < 8; ++ct) { f32x4 z = {0.f, 0.f, 0.f, 0.f}; acc[ct] = z; }

  #pragma unroll
  for (int ks = 0; ks < 4; ++ks) {
    const float* ap = A + (size_t)arow * FD + ks * 32 + kgrp * 8;
    float4 av0 = *reinterpret_cast<const float4*>(ap);
    float4 av1 = *reinterpret_cast<const float4*>(ap + 4);
    float a[8] = {av0.x, av0.y, av0.z, av0.w, av1.x, av1.y, av1.z, av1.w};
    bf16x8 ahi, alo;
    #pragma unroll
    for (int j = 0; j < 8; ++j) {
      float v = a[j];
      if (applyRelu) v = fmaxf(v, 0.f);
      unsigned int bb = __float_as_uint(v);
      unsigned int bh = bb & 0xFFFF0000u;
      float r = v - __uint_as_float(bh);  // exact
      ahi[j] = (short)(bh >> 16);
      alo[j] = (short)f2bf(r);
    }
    #pragma unroll
    for (int ct = 0; ct < 8; ++ct) {
      int off = (((ct * 4 + ks) * 2) * 64 + lane) * 8;
      bf16x8 bhi = *reinterpret_cast<const bf16x8*>(&ldsW[off]);
      bf16x8 blo = *reinterpret_cast<const bf16x8*>(&ldsW[off + 512]);
      acc[ct] = __builtin_amdgcn_mfma_f32_16x16x32_bf16(ahi, bhi, acc[ct], 0, 0, 0);
      acc[ct] = __builtin_amdgcn_mfma_f32_16x16x32_bf16(alo, bhi, acc[ct], 0, 0, 0);
      acc[ct] = __builtin_amdgcn_mfma_f32_16x16x32_bf16(ahi, blo, acc[ct], 0, 0, 0);
    }
  }

  // C layout: col = lane&15 (+16*ct), row = rowbase + (lane>>4)*4 + i
  int crow0 = rowbase + kgrp * 4;
  int ccol = lane & 15;
  #pragma unroll
  for (int i = 0; i < 4; ++i) {
    int r = crow0 + i;
    if (r < NN) {
      #pragma unroll
      for (int ct = 0; ct < 8; ++ct) {
        Hb[(size_t)r * FD + ct * 16 + ccol] = f2bf(acc[ct][i]);
      }
    }
  }
}

// ---------------- fused aggregation ----------------
// AGG[n][c] = b[c] + dis[n]^2 * H[n][c] + sum_e dis[src_e]*dis[n] * H[src_e][c]

__global__ __launch_bounds__(256) void agg_edge_kernel(const int* __restrict__ offs,
                                                       const unsigned short* __restrict__ csr,
                                                       const float* __restrict__ dis,
                                                       const unsigned short* __restrict__ Hb,
                                                       const float* __restrict__ b,
                                                       float* __restrict__ AGG) {
  int node = blockIdx.x * 4 + (threadIdx.x >> 6);
  if (node >= NN) return;
  node = __builtin_amdgcn_readfirstlane(node);
  int lane = threadIdx.x & 63;
  int half = lane >> 5;
  int ch = (lane & 31) * 4;
  int beg = offs[node], end = offs[node + 1];
  float disn = dis[node];

  float4 accA, accB = make_float4(0.f, 0.f, 0.f, 0.f);
  {
    float d2 = disn * disn;
    if (half == 0) {
      float4 bb = reinterpret_cast<const float4*>(b)[lane & 31];
      ushort4 hn = *reinterpret_cast<const ushort4*>(&Hb[(size_t)node * FD + ch]);
      accA = make_float4(bb.x + d2 * bf2f(hn.x), bb.y + d2 * bf2f(hn.y),
                         bb.z + d2 * bf2f(hn.z), bb.w + d2 * bf2f(hn.w));
    } else {
      accA = make_float4(0.f, 0.f, 0.f, 0.f);
    }
  }

  int j = beg;
  for (; j + 7 < end; j += 8) {
    int s0 = csr[j + 0 + half];
    int s1 = csr[j + 2 + half];
    int s2 = csr[j + 4 + half];
    int s3 = csr[j + 6 + half];
    float c0 = dis[s0] * disn;
    float c1 = dis[s1] * disn;
    float c2 = dis[s2] * disn;
    float c3 = dis[s3] * disn;
    ushort4 h0 = *reinterpret_cast<const ushort4*>(&Hb[(size_t)s0 * FD + ch]);
    ushort4 h1 = *reinterpret_cast<const ushort4*>(&Hb[(size_t)s1 * FD + ch]);
    ushort4 h2 = *reinterpret_cast<const ushort4*>(&Hb[(size_t)s2 * FD + ch]);
    ushort4 h3 = *reinterpret_cast<const ushort4*>(&Hb[(size_t)s3 * FD + ch]);
    accA.x += c0 * bf2f(h0.x); accA.y += c0 * bf2f(h0.y);
    accA.z += c0 * bf2f(h0.z); accA.w += c0 * bf2f(h0.w);
    accB.x += c1 * bf2f(h1.x); accB.y += c1 * bf2f(h1.y);
    accB.z += c1 * bf2f(h1.z); accB.w += c1 * bf2f(h1.w);
    accA.x += c2 * bf2f(h2.x); accA.y += c2 * bf2f(h2.y);
    accA.z += c2 * bf2f(h2.z); accA.w += c2 * bf2f(h2.w);
    accB.x += c3 * bf2f(h3.x); accB.y += c3 * bf2f(h3.y);
    accB.z += c3 * bf2f(h3.z); accB.w += c3 * bf2f(h3.w);
  }
  for (; j < end; j += 2) {
    int s0 = csr[j];
    float c0 = dis[s0] * disn;
    int s1 = s0; float c1 = 0.f;
    if (j + 1 < end) { s1 = csr[j + 1]; c1 = dis[s1] * disn; }
    int sa = half ? s1 : s0;  float ca = half ? c1 : c0;
    ushort4 ha = *reinterpret_cast<const ushort4*>(&Hb[(size_t)sa * FD + ch]);
    accA.x += ca * bf2f(ha.x); accA.y += ca * bf2f(ha.y);
    accA.z += ca * bf2f(ha.z); accA.w += ca * bf2f(ha.w);
  }
  accA.x += accB.x; accA.y += accB.y; accA.z += accB.z; accA.w += accB.w;

  accA.x += __shfl_xor(accA.x, 32, 64);
  accA.y += __shfl_xor(accA.y, 32, 64);
  accA.z += __shfl_xor(accA.z, 32, 64);
  accA.w += __shfl_xor(accA.w, 32, 64);

  if (half == 0) {
    reinterpret_cast<float4*>(AGG)[(size_t)node * 32 + (lane & 31)] = accA;
  }
}

// ---------------- fused pooling + classifier ----------------

__device__ __forceinline__ int lower_bound(const int* __restrict__ b, int n, int key) {
  int lo = 0, hi = n;
  while (lo < hi) {
    int m = (lo + hi) >> 1;
    if (b[m] < key) lo = m + 1; else hi = m;
  }
  return lo;
}

__global__ __launch_bounds__(256) void pool_final_kernel(const float* __restrict__ AGG,
                                                         const int* __restrict__ batch,
                                                         const float* __restrict__ Wl,
                                                         const float* __restrict__ bl,
                                                         float* __restrict__ out) {
  int g = blockIdx.x;
  int tid = threadIdx.x;
  int lane = tid & 63, w = tid >> 6;
  int start = lower_bound(batch, NN, g);
  int end = lower_bound(batch, NN, g + 1);

  const float2* AGG2 = reinterpret_cast<const float2*>(AGG);
  float2 acc = make_float2(0.f, 0.f);
  for (int n = start + w; n < end; n += 4) {
    float2 v = AGG2[(size_t)n * 64 + lane];
    acc.x += v.x; acc.y += v.y;
  }
  __shared__ float red[4][FD];
  red[w][lane * 2 + 0] = acc.x;
  red[w][lane * 2 + 1] = acc.y;
  __syncthreads();
  if (w == 0) {
    float px = red[0][lane * 2] + red[1][lane * 2] + red[2][lane * 2] + red[3][lane * 2];
    float py = red[0][lane * 2 + 1] + red[1][lane * 2 + 1] + red[2][lane * 2 + 1] + red[3][lane * 2 + 1];
    float inv = 1.0f / fmaxf((float)(end - start), 1.0f);
    px *= inv; py *= inv;
    float pc[NC];
    #pragma unroll
    for (int c = 0; c < NC; ++c)
      pc[c] = px * Wl[(2 * lane) * NC + c] + py * Wl[(2 * lane + 1) * NC + c];
    #pragma unroll
    for (int off = 32; off > 0; off >>= 1) {
      #pragma unroll
      for (int c = 0; c < NC; ++c) pc[c] += __shfl_down(pc[c], off, 64);
    }
    if (lane == 0) {
      #pragma unroll
      for (int c = 0; c < NC; ++c) out[g * NC + c] = pc[c] + bl[c];
    }
  }
}

// ---------------- launch ----------------

extern "C" void kernel_launch(void* const* d_in, const int* in_sizes, int n_in,
                              void* d_out, int out_size, void* d_ws, size_t ws_size,
                              hipStream_t stream) {
  const float* x       = (const float*)d_in[0];
  const int* ei        = (const int*)d_in[1];    // int32 on device
  const int* batch     = (const int*)d_in[2];    // int32 on device
  const float* W1 = (const float*)d_in[3];
  const float* b1 = (const float*)d_in[4];
  const float* W2 = (const float*)d_in[5];
  const float* b2 = (const float*)d_in[6];
  const float* W3 = (const float*)d_in[7];
  const float* b3 = (const float*)d_in[8];
  const float* Wl = (const float*)d_in[9];
  const float* bl = (const float*)d_in[10];
  float* out = (float*)d_out;

  char* ws = (char*)d_ws;
  size_t o = 0;
  auto alloc = [&](size_t bytes) {
    void* p = ws + o;
    o += bytes;
    o = (o + 255) & ~(size_t)255;
    return p;
  };
  int*   offs   = (int*)  alloc((size_t)(NN + 1) * 4);
  float* dis    = (float*)alloc((size_t)NN * 4);
  int*   gcur   = (int*)  alloc((size_t)NBUCK * 4);
  int*   bbase  = (int*)  alloc((size_t)NBUCK * 4);
  unsigned int* bucketBuf = (unsigned int*)alloc((size_t)NBUCK * BSTRIDE * 4);
  unsigned short* csr = (unsigned short*)alloc((size_t)NE * 2);
  unsigned short* hb  = (unsigned short*)alloc((size_t)NN * FD * 2);
  float* agg    = (float*)alloc((size_t)NN * FD * 4);
  unsigned short* wf1 = (unsigned short*)alloc((size_t)2 * FD * FD * 2);
  unsigned short* wf2 = (unsigned short*)alloc((size_t)2 * FD * FD * 2);
  unsigned short* wf3 = (unsigned short*)alloc((size_t)2 * FD * FD * 2);

  init_kernel<<<1, 128, 0, stream>>>(gcur);
  pass1_kernel<<<P1_BLOCKS, 1024, 0, stream>>>(ei, gcur, bucketBuf);
  bucket_scan_kernel<<<1, 128, 0, stream>>>(gcur, bbase);
  pass2_kernel<<<NBUCK, 1024, 0, stream>>>(bucketBuf, gcur, bbase, offs, dis, csr);
  prep_w_kernel<<<64, 256, 0, stream>>>(W1, wf1);
  prep_w_kernel<<<64, 256, 0, stream>>>(W2, wf2);
  prep_w_kernel<<<64, 256, 0, stream>>>(W3, wf3);

  int gemmGrid = (NN + 63) / 64;
  int nodeGrid = (NN + 3) / 4;

  // layer 1
  gemm_mfma_kernel<<<gemmGrid, 256, 0, stream>>>(x, wf1, hb, 0);
  agg_edge_kernel<<<nodeGrid, 256, 0, stream>>>(offs, csr, dis, hb, b1, agg);
  // layer 2
  gemm_mfma_kernel<<<gemmGrid, 256, 0, stream>>>(agg, wf2, hb, 1);
  agg_edge_kernel<<<nodeGrid, 256, 0, stream>>>(offs, csr, dis, hb, b2, agg);
  // layer 3
  gemm_mfma_kernel<<<gemmGrid, 256, 0, stream>>>(agg, wf3, hb, 1);
  agg_edge_kernel<<<nodeGrid, 256, 0, stream>>>(offs, csr, dis, hb, b3, agg);

  pool_final_kernel<<<NG, 256, 0, stream>>>(agg, batch, Wl, bl, out);
}